// Round 9
// baseline (572.470 us; speedup 1.0000x reference)
//
#include <hip/hip_runtime.h>
#include <math.h>

#define NN 50000
#define EE 800000
#define FF 128

constexpr float LN_EPS = 1e-5f;
constexpr int NC = (NN + 255) / 256;   // 196 scan chunks

typedef float  f32x4  __attribute__((ext_vector_type(4)));
typedef short  s16x8  __attribute__((ext_vector_type(8)));

__device__ __forceinline__ float silu_f(float v) {
    return v / (1.f + __expf(-v));
}

__device__ __forceinline__ unsigned short f2bf(float f) {
    union { float f; unsigned u; } cv; cv.f = f;
    unsigned u = cv.u;
    u += 0x7fffu + ((u >> 16) & 1u);   // round-to-nearest-even
    return (unsigned short)(u >> 16);
}

__device__ __forceinline__ float bf2f(unsigned short u) {
    union { unsigned u; float f; } cv; cv.u = ((unsigned)u) << 16;
    return cv.f;
}

// -------------------- prep: x -> bf16 --------------------
__global__ __launch_bounds__(256) void convert_x_kernel(
    const float* __restrict__ x, unsigned short* __restrict__ xb)
{
    int i = (blockIdx.x * 256 + threadIdx.x) * 8;
    float4 a = *(const float4*)&x[i];
    float4 b = *(const float4*)&x[i + 4];
    s16x8 o;
    o[0] = (short)f2bf(a.x); o[1] = (short)f2bf(a.y);
    o[2] = (short)f2bf(a.z); o[3] = (short)f2bf(a.w);
    o[4] = (short)f2bf(b.x); o[5] = (short)f2bf(b.y);
    o[6] = (short)f2bf(b.z); o[7] = (short)f2bf(b.w);
    *(s16x8*)&xb[i] = o;
}

// -------------------- prep: transpose all weights -> bf16 --------------------
__global__ __launch_bounds__(256) void transpose_w_kernel(
    const float* __restrict__ ew1, const float* __restrict__ ew2,
    const float* __restrict__ nw1, const float* __restrict__ nw2,
    unsigned short* __restrict__ ew1T, unsigned short* __restrict__ ew2T,
    unsigned short* __restrict__ nw1T, unsigned short* __restrict__ nw2T)
{
    int o = blockIdx.x * 256 + threadIdx.x;
    if (o < 32768) {
        int n = o >> 8, k = o & 255;
        ew1T[o] = f2bf(ew1[k * FF + n]);
    } else if (o < 49152) {
        int o2 = o - 32768; int n = o2 >> 7, k = o2 & 127;
        ew2T[o2] = f2bf(ew2[k * FF + n]);
    } else if (o < 65536) {
        int o2 = o - 49152; int n = o2 >> 7, k = o2 & 127;
        nw1T[o2] = f2bf(nw1[k * FF + n]);
    } else {
        int o2 = o - 65536; int n = o2 >> 7, k = o2 & 127;
        nw2T[o2] = f2bf(nw2[k * FF + n]);
    }
}

// -------------------- counting sort by row --------------------
__global__ __launch_bounds__(256) void hist_kernel(
    const int* __restrict__ ei, int* __restrict__ cnt)
{
    int e = blockIdx.x * 256 + threadIdx.x;
    if (e < EE) atomicAdd(&cnt[ei[e]], 1);
}

__global__ __launch_bounds__(256) void chunk_sum_kernel(
    const int* __restrict__ cnt, int* __restrict__ chunkSum)
{
    __shared__ int s[256];
    int t = threadIdx.x;
    int idx = blockIdx.x * 256 + t;
    s[t] = (idx < NN) ? cnt[idx] : 0;
    __syncthreads();
    for (int off = 128; off > 0; off >>= 1) {
        if (t < off) s[t] += s[t + off];
        __syncthreads();
    }
    if (t == 0) chunkSum[blockIdx.x] = s[0];
}

__global__ __launch_bounds__(256) void scan_chunks_kernel(
    const int* __restrict__ chunkSum, int* __restrict__ chunkOff)
{
    __shared__ int s[256];
    int t = threadIdx.x;
    int v = (t < NC) ? chunkSum[t] : 0;
    s[t] = v;
    __syncthreads();
    for (int off = 1; off < 256; off <<= 1) {
        int u = (t >= off) ? s[t - off] : 0;
        __syncthreads();
        s[t] += u;
        __syncthreads();
    }
    if (t < NC) chunkOff[t] = s[t] - v;
}

__global__ __launch_bounds__(256) void scan_kernel(
    const int* __restrict__ cnt, const int* __restrict__ chunkOff,
    int* __restrict__ offs, int* __restrict__ rowStart)
{
    __shared__ int s[256];
    int t = threadIdx.x;
    int idx = blockIdx.x * 256 + t;
    int v = (idx < NN) ? cnt[idx] : 0;
    s[t] = v;
    __syncthreads();
    for (int off = 1; off < 256; off <<= 1) {
        int u = (t >= off) ? s[t - off] : 0;
        __syncthreads();
        s[t] += u;
        __syncthreads();
    }
    if (idx < NN) {
        int st = chunkOff[blockIdx.x] + s[t] - v;
        offs[idx] = st;
        rowStart[idx] = st;
    }
}

__global__ __launch_bounds__(256) void scatter_idx_kernel(
    const int* __restrict__ ei, int* __restrict__ offs,
    int2* __restrict__ sRC)
{
    int e = blockIdx.x * 256 + threadIdx.x;
    if (e < EE) {
        int r = ei[e], c = ei[EE + e];
        int p = atomicAdd(&offs[r], 1);
        sRC[p] = make_int2(r, c);
    }
}

// ==================== PASS A: edge MLP -> msgb, sSg (pipelined) ===========
constexpr int EPB   = 64;
constexpr int NTILE = EE / EPB;    // 12500
constexpr int XAS   = 264;         // xa stride: 528 B row (33 quads, odd)
constexpr int H1S   = 136;         // h1/msgL stride: 272 B row (17 quads, odd)

__global__ __launch_bounds__(512, 4) void edgeA_kernel(
    const unsigned short* __restrict__ xb, const float* __restrict__ pos,
    const int2* __restrict__ sRC,
    const unsigned short* __restrict__ ew1T, const float* __restrict__ ew1,
    const float* __restrict__ eb1,
    const unsigned short* __restrict__ ew2T, const float* __restrict__ eb2,
    const float* __restrict__ cw,  const float* __restrict__ cb,
    unsigned short* __restrict__ msgb, float* __restrict__ sSg)
{
    __shared__ float dist2S[EPB];
    __shared__ float sPart[8][EPB];
    __shared__ __align__(16) unsigned short xa  [EPB * XAS];
    __shared__ __align__(16) unsigned short h1  [EPB * H1S];
    __shared__ __align__(16) unsigned short msgL[EPB * H1S];

    const int t   = threadIdx.x;
    const int w   = t >> 6;
    const int l   = t & 63;
    const int l15 = l & 15;
    const int q8  = l >> 4;
    const int n   = w * 16 + l15;

    s16x8 B1[8], B2[4];
    #pragma unroll
    for (int ko = 0; ko < 8; ++ko)
        B1[ko] = *(const s16x8*)(ew1T + (size_t)n * 256 + ko * 32 + q8 * 8);
    #pragma unroll
    for (int ko = 0; ko < 4; ++ko)
        B2[ko] = *(const s16x8*)(ew2T + (size_t)n * 128 + ko * 32 + q8 * 8);
    const float w256 = ew1[256 * FF + n];
    const float b1   = eb1[n];
    const float b2   = eb2[n];
    const float cwc  = cw[n];
    const float cb0  = cb[0];

    const int q    = t & 31;                  // 0..15 row-half, 16..31 col-half
    const int eB   = t >> 5;                  // 0..15
    const int ksel = (q & 15) * 8;
    const bool useRow = (q < 16);

    int   nidx[4];
    s16x8 ag[4];
    {
        int e0 = blockIdx.x * EPB;
        #pragma unroll
        for (int i = 0; i < 4; ++i) {
            int2 rc = sRC[e0 + eB + 16 * i];
            nidx[i] = useRow ? rc.x : rc.y;
        }
        #pragma unroll
        for (int i = 0; i < 4; ++i) ag[i] = *(const s16x8*)(xb + (size_t)nidx[i] * FF + ksel);
    }

    for (int tile = blockIdx.x; tile < NTILE; tile += gridDim.x) {
        const int e0 = tile * EPB;

        #pragma unroll
        for (int i = 0; i < 4; ++i)
            *(s16x8*)(xa + (eB + 16 * i) * XAS + q * 8) = ag[i];
        if (t < EPB) {
            int2 rc = sRC[e0 + t];
            int r = rc.x, c = rc.y;
            float dx = pos[r*3+0] - pos[c*3+0];
            float dy = pos[r*3+1] - pos[c*3+1];
            float dz = pos[r*3+2] - pos[c*3+2];
            dist2S[t] = dx*dx + dy*dy + dz*dz;
        }
        __syncthreads();   // (A)

        {
            int tn  = tile + gridDim.x;
            int e0n = (tn < NTILE) ? tn * EPB : 0;
            #pragma unroll
            for (int i = 0; i < 4; ++i) {
                int2 rc = sRC[e0n + eB + 16 * i];
                nidx[i] = useRow ? rc.x : rc.y;
            }
            #pragma unroll
            for (int i = 0; i < 4; ++i) ag[i] = *(const s16x8*)(xb + (size_t)nidx[i] * FF + ksel);
        }

        f32x4 acc[4] = {};
        #pragma unroll
        for (int mt = 0; mt < 4; ++mt) {
            const unsigned short* ar = xa + (mt * 16 + l15) * XAS + q8 * 8;
            #pragma unroll
            for (int ko = 0; ko < 8; ++ko) {
                s16x8 a = *(const s16x8*)(ar + ko * 32);
                acc[mt] = __builtin_amdgcn_mfma_f32_16x16x32_bf16(a, B1[ko], acc[mt], 0, 0, 0);
            }
        }

        #pragma unroll
        for (int mt = 0; mt < 4; ++mt) {
            #pragma unroll
            for (int r = 0; r < 4; ++r) {
                int e = mt * 16 + q8 * 4 + r;
                float v = acc[mt][r] + dist2S[e] * w256 + b1;
                h1[e * H1S + n] = f2bf(silu_f(v));
            }
        }
        __syncthreads();   // (B)

        f32x4 acc2[4] = {};
        #pragma unroll
        for (int mt = 0; mt < 4; ++mt) {
            const unsigned short* hr = h1 + (mt * 16 + l15) * H1S + q8 * 8;
            #pragma unroll
            for (int ko = 0; ko < 4; ++ko) {
                s16x8 a = *(const s16x8*)(hr + ko * 32);
                acc2[mt] = __builtin_amdgcn_mfma_f32_16x16x32_bf16(a, B2[ko], acc2[mt], 0, 0, 0);
            }
        }

        #pragma unroll
        for (int mt = 0; mt < 4; ++mt) {
            #pragma unroll
            for (int r = 0; r < 4; ++r) {
                float m = acc2[mt][r] + b2;
                float p = m * cwc;
                p += __shfl_xor(p, 1);
                p += __shfl_xor(p, 2);
                p += __shfl_xor(p, 4);
                p += __shfl_xor(p, 8);
                int e = mt * 16 + q8 * 4 + r;
                if (l15 == 0) sPart[w][e] = p;
                msgL[e * H1S + n] = f2bf(m);
            }
        }
        __syncthreads();   // (C)

        if (t < EPB) {
            float p = 0.f;
            #pragma unroll
            for (int ww = 0; ww < 8; ++ww) p += sPart[ww][t];
            sSg[e0 + t] = tanhf(p + cb0);
        }

        #pragma unroll
        for (int i = 0; i < 2; ++i) {
            int idx = i * 512 + t;
            int e   = idx >> 4;
            int c   = idx & 15;
            *(s16x8*)&msgb[(size_t)(e0 + e) * FF + c * 8] =
                *(const s16x8*)&msgL[e * H1S + c * 8];
        }
    }
}

// ==================== PASS B1: streaming segmented reduce =================
// Block owns 64 nodes -> one contiguous edge slab [rowStart[n0], rowStart[n0+64)).
// 16-lane group streams 16 consecutive rows; register-accumulate per node,
// flush to LDS f32 tile via ds atomics only on node change.
constexpr int NB1 = 64;
constexpr int AST = 132;   // f32 LDS stride (528 B row, odd quads)

__global__ __launch_bounds__(512) void aggB_kernel(
    const unsigned short* __restrict__ msgb, const float* __restrict__ sSg,
    const int2* __restrict__ sRC, const int* __restrict__ rowStart,
    const float* __restrict__ pos,
    unsigned short* __restrict__ aggB, float* __restrict__ delta)
{
    __shared__ float aggL[NB1 * AST];   // 33792 B
    __shared__ float dL[NB1 * 3];

    const int t  = threadIdx.x;
    const int g  = t >> 4;          // group 0..31
    const int c8 = (t & 15) * 8;    // this thread's 8-col slice
    const int n0 = blockIdx.x * NB1;

    for (int i = t; i < NB1 * AST; i += 512) aggL[i] = 0.f;
    if (t < NB1 * 3) dL[t] = 0.f;
    __syncthreads();

    const int p0 = rowStart[n0];
    const int p1 = (n0 + NB1 >= NN) ? EE : rowStart[n0 + NB1];

    // phase 1: agg stream-reduce
    float acc[8];
    #pragma unroll
    for (int j = 0; j < 8; ++j) acc[j] = 0.f;
    int cur = -1;

    for (int base = p0 + g * 16; base < p1; base += 512) {
        // preload the 16 row ids (broadcast across the 16-lane group)
        int rr[16];
        #pragma unroll
        for (int i = 0; i < 16; ++i) {
            int p = base + i;
            rr[i] = sRC[(p < EE) ? p : (EE - 1)].x;
        }
        #pragma unroll
        for (int i = 0; i < 16; ++i) {
            int p = base + i;
            if (p < p1) {
                int r = rr[i];
                if (r != cur) {
                    if (cur >= 0) {
                        float* dst = aggL + (cur - n0) * AST + c8;
                        #pragma unroll
                        for (int j = 0; j < 8; ++j) atomicAdd(dst + j, acc[j]);
                    }
                    cur = r;
                    #pragma unroll
                    for (int j = 0; j < 8; ++j) acc[j] = 0.f;
                }
                s16x8 v = *(const s16x8*)(msgb + (size_t)p * FF + c8);
                #pragma unroll
                for (int j = 0; j < 8; ++j) acc[j] += bf2f((unsigned short)v[j]);
            }
        }
    }
    if (cur >= 0) {
        float* dst = aggL + (cur - n0) * AST + c8;
        #pragma unroll
        for (int j = 0; j < 8; ++j) atomicAdd(dst + j, acc[j]);
    }

    // phase 2: delta (all 512 threads, coalesced sRC/sSg, pos[c] via L2, TLP-hidden)
    for (int p = p0 + t; p < p1; p += 512) {
        int2 rc = sRC[p];
        float s = sSg[p];
        int r = rc.x, c = rc.y;
        float* dd = dL + (r - n0) * 3;
        atomicAdd(dd + 0, s * (pos[r*3+0] - pos[c*3+0]));
        atomicAdd(dd + 1, s * (pos[r*3+1] - pos[c*3+1]));
        atomicAdd(dd + 2, s * (pos[r*3+2] - pos[c*3+2]));
    }
    __syncthreads();

    // store: aggL -> aggB (bf16, dense), dL -> delta (f32, dense)
    for (int idx = t; idx < NB1 * 16; idx += 512) {
        int e = idx >> 4, c = (idx & 15) * 8;
        if (n0 + e < NN) {
            s16x8 o;
            #pragma unroll
            for (int j = 0; j < 8; ++j) o[j] = (short)f2bf(aggL[e * AST + c + j]);
            *(s16x8*)(aggB + (size_t)(n0 + e) * FF + c) = o;
        }
    }
    if (t < NB1 * 3) {
        int e = t / 3;
        if (n0 + e < NN) delta[(size_t)(n0 + e) * 3 + (t % 3)] = dL[t];
    }
}

// ==================== PASS B2: dense MFMA node MLP + LN + pos =============
constexpr int NPB2 = 32;
constexpr int XTS  = 132;   // x tile f32 stride
constexpr int HBS  = 136;   // h1 bf16 stride

__global__ __launch_bounds__(512) void nodeC_kernel(
    const float* __restrict__ x, const float* __restrict__ pos,
    const unsigned short* __restrict__ aggB, const float* __restrict__ delta,
    const unsigned short* __restrict__ nw1T, const float* __restrict__ nb1,
    const unsigned short* __restrict__ nw2T, const float* __restrict__ nb2,
    const float* __restrict__ gamma, const float* __restrict__ beta,
    float* __restrict__ xout, float* __restrict__ posout)
{
    __shared__ __align__(16) float xT[NPB2 * XTS];            // 16.9 KB
    __shared__ __align__(16) unsigned short h1B[NPB2 * HBS];  // 8.7 KB
    __shared__ float sRedS[8][NPB2];
    __shared__ float sRedQ[8][NPB2];

    const int t   = threadIdx.x;
    const int w   = t >> 6;          // 0..7
    const int l   = t & 63;
    const int l15 = l & 15;
    const int q8  = l >> 4;
    const int n0  = blockIdx.x * NPB2;
    const int n   = w * 16 + l15;    // this wave's output column

    // stage x tile (vectorized; clamp last block)
    #pragma unroll
    for (int i = 0; i < 2; ++i) {
        int idx = i * 512 + t;
        int e = idx >> 5, c = (idx & 31) * 4;
        int ee = (n0 + e < NN) ? (n0 + e) : (NN - 1);
        *(float4*)&xT[e * XTS + c] = *(const float4*)&x[(size_t)ee * FF + c];
    }
    // posout = pos + delta (delta aliased in posout region; same-thread RMW)
    if (t < NPB2 * 3) {
        int e = t / 3, d = t % 3;
        int nn = n0 + e;
        if (nn < NN)
            posout[(size_t)nn * 3 + d] = pos[(size_t)nn * 3 + d] + delta[(size_t)nn * 3 + d];
    }

    // GEMM1 (32 nodes x 128 cols, K=128): A direct from global bf16 agg
    f32x4 acc[2] = {};
    #pragma unroll
    for (int mt = 0; mt < 2; ++mt) {
        int row = n0 + mt * 16 + l15;
        if (row >= NN) row = NN - 1;
        const unsigned short* ar = aggB + (size_t)row * FF + q8 * 8;
        #pragma unroll
        for (int ko = 0; ko < 4; ++ko) {
            s16x8 a = *(const s16x8*)(ar + ko * 32);
            s16x8 b = *(const s16x8*)(nw1T + (size_t)n * 128 + ko * 32 + q8 * 8);
            acc[mt] = __builtin_amdgcn_mfma_f32_16x16x32_bf16(a, b, acc[mt], 0, 0, 0);
        }
    }
    {
        float bb = nb1[n];
        #pragma unroll
        for (int mt = 0; mt < 2; ++mt)
            #pragma unroll
            for (int r = 0; r < 4; ++r) {
                int e = mt * 16 + q8 * 4 + r;
                h1B[e * HBS + n] = f2bf(silu_f(acc[mt][r] + bb));
            }
    }
    __syncthreads();

    // GEMM2 (K=128)
    f32x4 acc2[2] = {};
    #pragma unroll
    for (int mt = 0; mt < 2; ++mt) {
        const unsigned short* hr = h1B + (mt * 16 + l15) * HBS + q8 * 8;
        #pragma unroll
        for (int ko = 0; ko < 4; ++ko) {
            s16x8 a = *(const s16x8*)(hr + ko * 32);
            s16x8 b = *(const s16x8*)(nw2T + (size_t)n * 128 + ko * 32 + q8 * 8);
            acc2[mt] = __builtin_amdgcn_mfma_f32_16x16x32_bf16(a, b, acc2[mt], 0, 0, 0);
        }
    }

    // residual + LN
    float pre[2][4];
    {
        float bb = nb2[n];
        #pragma unroll
        for (int mt = 0; mt < 2; ++mt)
            #pragma unroll
            for (int r = 0; r < 4; ++r) {
                int e = mt * 16 + q8 * 4 + r;
                pre[mt][r] = xT[e * XTS + n] + acc2[mt][r] + bb;
            }
    }
    #pragma unroll
    for (int mt = 0; mt < 2; ++mt)
        #pragma unroll
        for (int r = 0; r < 4; ++r) {
            float s = pre[mt][r], sq = pre[mt][r] * pre[mt][r];
            s += __shfl_xor(s, 1);  sq += __shfl_xor(sq, 1);
            s += __shfl_xor(s, 2);  sq += __shfl_xor(sq, 2);
            s += __shfl_xor(s, 4);  sq += __shfl_xor(sq, 4);
            s += __shfl_xor(s, 8);  sq += __shfl_xor(sq, 8);
            if (l15 == 0) {
                int e = mt * 16 + q8 * 4 + r;
                sRedS[w][e] = s;
                sRedQ[w][e] = sq;
            }
        }
    __syncthreads();

    {
        float g = gamma[n], bt = beta[n];
        #pragma unroll
        for (int mt = 0; mt < 2; ++mt)
            #pragma unroll
            for (int r = 0; r < 4; ++r) {
                int e = mt * 16 + q8 * 4 + r;
                int nn = n0 + e;
                if (nn < NN) {
                    float S = 0.f, Q = 0.f;
                    #pragma unroll
                    for (int ww = 0; ww < 8; ++ww) { S += sRedS[ww][e]; Q += sRedQ[ww][e]; }
                    float mean = S * (1.f / FF);
                    float var  = Q * (1.f / FF) - mean * mean;
                    xout[(size_t)nn * FF + n] =
                        g * (pre[mt][r] - mean) * rsqrtf(var + LN_EPS) + bt;
                }
            }
    }
}

// -------------------- launcher --------------------
extern "C" void kernel_launch(void* const* d_in, const int* in_sizes, int n_in,
                              void* d_out, int out_size, void* d_ws, size_t ws_size,
                              hipStream_t stream) {
    const float* x    = (const float*)d_in[0];
    const float* pos  = (const float*)d_in[1];
    const int*   ei   = (const int*)  d_in[2];
    const float* ew1  = (const float*)d_in[3];
    const float* eb1  = (const float*)d_in[4];
    const float* ew2  = (const float*)d_in[5];
    const float* eb2  = (const float*)d_in[6];
    const float* nw1  = (const float*)d_in[7];
    const float* nb1  = (const float*)d_in[8];
    const float* nw2  = (const float*)d_in[9];
    const float* nb2  = (const float*)d_in[10];
    const float* cw   = (const float*)d_in[11];
    const float* cb   = (const float*)d_in[12];
    const float* gam  = (const float*)d_in[13];
    const float* bet  = (const float*)d_in[14];

    float* out    = (float*)d_out;
    float* xout   = out;
    float* posout = out + (size_t)NN * FF;

    auto align256 = [](size_t v) { return (v + 255) & ~(size_t)255; };
    char* ws = (char*)d_ws;

    size_t CNT_B   = align256((size_t)NN * 4);
    size_t OFFS_B  = align256((size_t)NN * 4);
    size_t RST_B   = align256((size_t)NN * 4);
    size_t CHNK_B  = align256((size_t)NC * 4 * 2);
    size_t SRC_B   = align256((size_t)EE * 8);        // int2
    size_t XB_B    = align256((size_t)NN * FF * 2);
    size_t EW1T_B  = align256((size_t)128 * 256 * 2);
    size_t WT_B    = align256((size_t)128 * 128 * 2);
    size_t MSGB_B  = align256((size_t)EE * FF * 2);   // 204.8 MB

    size_t o = 0;
    int* cnt       = (int*)(ws + o);  o += CNT_B;    // zeroed
    int* offs      = (int*)(ws + o);  o += OFFS_B;
    int* rowStart  = (int*)(ws + o);  o += RST_B;
    int* chunkSum  = (int*)(ws + o);
    int* chunkOff  = chunkSum + NC;   o += CHNK_B;
    int2* sRC      = (int2*)(ws + o); o += SRC_B;
    unsigned short* xb   = (unsigned short*)(ws + o);  o += XB_B;
    unsigned short* ew1T = (unsigned short*)(ws + o);  o += EW1T_B;
    unsigned short* ew2T = (unsigned short*)(ws + o);  o += WT_B;
    unsigned short* nw1T = (unsigned short*)(ws + o);  o += WT_B;
    unsigned short* nw2T = (unsigned short*)(ws + o);  o += WT_B;
    unsigned short* msgb = (unsigned short*)(ws + o);  o += MSGB_B;
    float*          sSg  = (float*)(ws + o);

    // aliases: aggB reuses xb (dead after edgeA); delta scratch lives in posout
    unsigned short* aggB  = xb;
    float*          delta = posout;

    hipMemsetAsync(cnt, 0, CNT_B, stream);

    convert_x_kernel<<<(NN * FF / 8) / 256, 256, 0, stream>>>(x, xb);
    transpose_w_kernel<<<(32768 + 3 * 16384) / 256, 256, 0, stream>>>(
        ew1, ew2, nw1, nw2, ew1T, ew2T, nw1T, nw2T);

    hist_kernel<<<(EE + 255) / 256, 256, 0, stream>>>(ei, cnt);
    chunk_sum_kernel<<<NC, 256, 0, stream>>>(cnt, chunkSum);
    scan_chunks_kernel<<<1, 256, 0, stream>>>(chunkSum, chunkOff);
    scan_kernel<<<NC, 256, 0, stream>>>(cnt, chunkOff, offs, rowStart);
    scatter_idx_kernel<<<(EE + 255) / 256, 256, 0, stream>>>(ei, offs, sRC);

    edgeA_kernel<<<2048, 512, 0, stream>>>(
        xb, pos, sRC, ew1T, ew1, eb1, ew2T, eb2, cw, cb, msgb, sSg);

    aggB_kernel<<<(NN + NB1 - 1) / NB1, 512, 0, stream>>>(
        msgb, sSg, sRC, rowStart, pos, aggB, delta);

    nodeC_kernel<<<(NN + NPB2 - 1) / NPB2, 512, 0, stream>>>(
        x, pos, aggB, delta, nw1T, nb1, nw2T, nb2, gam, bet, xout, posout);
}